// Round 2
// baseline (693.361 us; speedup 1.0000x reference)
//
#include <hip/hip_runtime.h>
#include <hip/hip_fp16.h>
#include <math.h>

#define N_NODES 30000
#define E_EDGES 480000
#define VD      512
#define HID     32

// ws layout (bytes):
//   [0, 120000)        acc  (float, zeroed by k_prep*)
//   [120000, 240000)   deg  (float, zeroed by k_prep*)
//   [240000, 360000)   sarr (float, fully written by k_pre)
//   fp16 path: [360448, 360448+30,720,000)  nvis: normalized fp16 rows (1024 B each)
//   fp32 path: [360000, 480000)             inv: inverse norms
#define ACC_OFF  0
#define DEG_OFF  30000
#define SARR_OFF 60000
#define INV_OFF  90000
#define NV_BYTE_OFF 360448u

// ---------------- k_pre: BN stats from 5 moments + per-node scalar s[] ----------------
// Single block of 1024 threads. s[n] = sb + sum_c prelu(bn(h1))_c * u_c where
// u = (wp . wc) . w2 — everything after PReLU is linear and projects to a scalar.
__global__ void __launch_bounds__(1024) k_pre(
        const float* __restrict__ x,
        const float* __restrict__ w1, const float* __restrict__ b1,
        const float* __restrict__ gamma, const float* __restrict__ beta,
        const float* __restrict__ prelu_a,
        const float* __restrict__ w2, const float* __restrict__ b2,
        const float* __restrict__ wc, const float* __restrict__ wp,
        float* __restrict__ sarr, int n) {
    __shared__ float red[16][5];
    __shared__ float s_scale[HID], s_shift[HID], s_u[HID], s_w1a[HID], s_w1b[HID];
    __shared__ float s_wpc[HID];
    __shared__ float s_sb;
    int t = threadIdx.x;
    float s0 = 0.f, s1 = 0.f, s00 = 0.f, s11 = 0.f, s01 = 0.f;
    for (int i = t; i < n; i += 1024) {
        float2 v = ((const float2*)x)[i];
        s0  += v.x;       s1  += v.y;
        s00 += v.x * v.x; s11 += v.y * v.y;
        s01 += v.x * v.y;
    }
    for (int o = 32; o; o >>= 1) {
        s0  += __shfl_xor(s0,  o, 64);
        s1  += __shfl_xor(s1,  o, 64);
        s00 += __shfl_xor(s00, o, 64);
        s11 += __shfl_xor(s11, o, 64);
        s01 += __shfl_xor(s01, o, 64);
    }
    int wv = t >> 6;
    if ((t & 63) == 0) {
        red[wv][0] = s0; red[wv][1] = s1; red[wv][2] = s00;
        red[wv][3] = s11; red[wv][4] = s01;
    }
    __syncthreads();
    if (t < HID) {
        float S0 = 0, S1 = 0, S00 = 0, S11 = 0, S01 = 0;
        for (int w = 0; w < 16; ++w) {
            S0 += red[w][0]; S1 += red[w][1]; S00 += red[w][2];
            S11 += red[w][3]; S01 += red[w][4];
        }
        float wpck = 0.f;
        for (int j = 0; j < HID; ++j) wpck += wp[j] * wc[j * HID + t];
        s_wpc[t] = wpck;
        const float invN = 1.0f / (float)n;
        float m0  = S0 * invN, m1 = S1 * invN;
        float v0  = fmaxf(S00 * invN - m0 * m0, 0.f);
        float v1  = fmaxf(S11 * invN - m1 * m1, 0.f);
        float c01 = S01 * invN - m0 * m1;
        float a0 = w1[2 * t], a1 = w1[2 * t + 1];
        float mean = a0 * m0 + a1 * m1 + b1[t];
        float var  = fmaxf(a0 * a0 * v0 + a1 * a1 * v1 + 2.f * a0 * a1 * c01, 0.f);
        float rs    = 1.0f / sqrtf(var + 1e-5f);
        float scale = gamma[t] * rs;
        s_scale[t] = scale;
        s_shift[t] = beta[t] - mean * scale;
        s_w1a[t] = a0; s_w1b[t] = a1;
    }
    __syncthreads();
    if (t < HID) {
        float uu = 0.f;
        for (int k = 0; k < HID; ++k) uu += s_wpc[k] * w2[k * HID + t];
        s_u[t] = uu;
    }
    if (t == 0) {
        float sb = 0.f;
        for (int k = 0; k < HID; ++k) sb += s_wpc[k] * b2[k];
        s_sb = sb;
    }
    __syncthreads();
    const float aslope = prelu_a[0];
    const float sb = s_sb;
    for (int i = t; i < n; i += 1024) {
        float2 xv = ((const float2*)x)[i];
        float sacc = sb;
        #pragma unroll
        for (int c = 0; c < HID; ++c) {
            float h  = s_w1a[c] * xv.x + s_w1b[c] * xv.y + b1[c];
            float tt = h * s_scale[c] + s_shift[c];
            tt = tt >= 0.f ? tt : aslope * tt;
            sacc += tt * s_u[c];
        }
        sarr[i] = sacc;
    }
}

// ---------------- k_prep16: normalize rows -> fp16, zero acc/deg ----------------
__global__ void __launch_bounds__(256) k_prep16(const float* __restrict__ visual,
                                                float* __restrict__ ws, int n) {
    int gid = blockIdx.x * blockDim.x + threadIdx.x;
    if (gid < 2 * N_NODES) ws[gid] = 0.f;  // acc + deg
    ushort* nvis = (ushort*)((char*)ws + NV_BYTE_OFF);
    int wave  = gid >> 6;
    int lane  = threadIdx.x & 63;
    int nwave = (gridDim.x * blockDim.x) >> 6;
    for (int node = wave; node < n; node += nwave) {
        const float4* row = (const float4*)(visual + (size_t)node * VD);
        float4 a = row[lane];
        float4 b = row[lane + 64];
        float p = a.x*a.x + a.y*a.y + a.z*a.z + a.w*a.w
                + b.x*b.x + b.y*b.y + b.z*b.z + b.w*b.w;
        for (int o = 32; o; o >>= 1) p += __shfl_xor(p, o, 64);
        float r = 1.0f / fmaxf(sqrtf(p), 1e-8f);
        __half2 p0 = __floats2half2_rn(a.x * r, a.y * r);
        __half2 p1 = __floats2half2_rn(a.z * r, a.w * r);
        __half2 p2 = __floats2half2_rn(b.x * r, b.y * r);
        __half2 p3 = __floats2half2_rn(b.z * r, b.w * r);
        uint2* orow = (uint2*)(nvis + (size_t)node * VD);
        uint2 q0, q1;
        q0.x = *(unsigned int*)&p0; q0.y = *(unsigned int*)&p1;
        q1.x = *(unsigned int*)&p2; q1.y = *(unsigned int*)&p3;
        orow[lane]      = q0;
        orow[lane + 64] = q1;
    }
}

// ---------------- k_edge16: cosine (pre-normalized fp16) + scalar scatter ----------------
__device__ inline float2 h2f(unsigned int u) {
    __half2 h = *reinterpret_cast<__half2*>(&u);
    return __half22float2(h);
}

__global__ void __launch_bounds__(256) k_edge16(const int* __restrict__ ei,
                                                const float* __restrict__ ws_ro,
                                                float* __restrict__ acc,
                                                float* __restrict__ deg,
                                                const float* __restrict__ sarr) {
    const uint4* nvis = (const uint4*)((const char*)ws_ro + NV_BYTE_OFF);
    int wave  = (blockIdx.x * blockDim.x + threadIdx.x) >> 6;
    int lane  = threadIdx.x & 63;
    int nwave = (gridDim.x * blockDim.x) >> 6;
    for (int e = wave; e < E_EDGES; e += nwave) {
        int s = ei[e];
        int d = ei[E_EDGES + e];
        uint4 A = nvis[(size_t)s * 64 + lane];
        uint4 B = nvis[(size_t)d * 64 + lane];
        float2 a0 = h2f(A.x), a1 = h2f(A.y), a2 = h2f(A.z), a3 = h2f(A.w);
        float2 b0 = h2f(B.x), b1 = h2f(B.y), b2 = h2f(B.z), b3 = h2f(B.w);
        float p = a0.x*b0.x + a0.y*b0.y + a1.x*b1.x + a1.y*b1.y
                + a2.x*b2.x + a2.y*b2.y + a3.x*b3.x + a3.y*b3.y;
        for (int o = 32; o; o >>= 1) p += __shfl_xor(p, o, 64);
        if (lane == 0) {
            atomicAdd(&acc[d], p * sarr[s]);
            atomicAdd(&deg[d], 1.0f);
        }
    }
}

// ---------------- fp32 fallback path (if ws too small) ----------------
__global__ void __launch_bounds__(256) k_prep32(const float* __restrict__ visual,
                                                float* __restrict__ ws, int n) {
    int gid = blockIdx.x * blockDim.x + threadIdx.x;
    if (gid < 2 * N_NODES) ws[gid] = 0.f;
    float* inv = ws + INV_OFF;
    int wave  = gid >> 6;
    int lane  = threadIdx.x & 63;
    int nwave = (gridDim.x * blockDim.x) >> 6;
    for (int node = wave; node < n; node += nwave) {
        const float4* row = (const float4*)(visual + (size_t)node * VD);
        float4 a = row[lane];
        float4 b = row[lane + 64];
        float p = a.x*a.x + a.y*a.y + a.z*a.z + a.w*a.w
                + b.x*b.x + b.y*b.y + b.z*b.z + b.w*b.w;
        for (int o = 32; o; o >>= 1) p += __shfl_xor(p, o, 64);
        if (lane == 0) inv[node] = 1.0f / fmaxf(sqrtf(p), 1e-8f);
    }
}

__global__ void __launch_bounds__(256) k_edge32(const int* __restrict__ ei,
                                                const float* __restrict__ visual,
                                                const float* __restrict__ inv,
                                                const float* __restrict__ sarr,
                                                float* __restrict__ acc,
                                                float* __restrict__ deg) {
    int wave  = (blockIdx.x * blockDim.x + threadIdx.x) >> 6;
    int lane  = threadIdx.x & 63;
    int nwave = (gridDim.x * blockDim.x) >> 6;
    for (int e = wave; e < E_EDGES; e += nwave) {
        int s = ei[e];
        int d = ei[E_EDGES + e];
        const float4* ra = (const float4*)(visual + (size_t)s * VD);
        const float4* rb = (const float4*)(visual + (size_t)d * VD);
        float4 a0 = ra[lane];
        float4 b0 = rb[lane];
        float4 a1 = ra[lane + 64];
        float4 b1 = rb[lane + 64];
        float p = a0.x*b0.x + a0.y*b0.y + a0.z*b0.z + a0.w*b0.w
                + a1.x*b1.x + a1.y*b1.y + a1.z*b1.z + a1.w*b1.w;
        for (int o = 32; o; o >>= 1) p += __shfl_xor(p, o, 64);
        if (lane == 0) {
            float w = p * inv[s] * inv[d];
            atomicAdd(&acc[d], w * sarr[s]);
            atomicAdd(&deg[d], 1.0f);
        }
    }
}

// ---------------- k_final ----------------
__global__ void k_final(const float* __restrict__ acc, const float* __restrict__ deg,
                        const float* __restrict__ bc, const float* __restrict__ wp,
                        const float* __restrict__ bp, float* __restrict__ out, int n) {
    float K = bp[0];
    #pragma unroll
    for (int j = 0; j < HID; ++j) K += wp[j] * bc[j];
    for (int i = blockIdx.x * blockDim.x + threadIdx.x; i < n; i += gridDim.x * blockDim.x) {
        out[i] = acc[i] / fmaxf(deg[i], 1.0f) + K;
    }
}

extern "C" void kernel_launch(void* const* d_in, const int* in_sizes, int n_in,
                              void* d_out, int out_size, void* d_ws, size_t ws_size,
                              hipStream_t stream) {
    const float* x       = (const float*)d_in[0];
    const float* visual  = (const float*)d_in[1];
    const int*   ei      = (const int*)  d_in[2];
    const float* w1      = (const float*)d_in[3];
    const float* b1      = (const float*)d_in[4];
    const float* gamma   = (const float*)d_in[5];
    const float* beta    = (const float*)d_in[6];
    const float* prelu_a = (const float*)d_in[7];
    const float* w2      = (const float*)d_in[8];
    const float* b2      = (const float*)d_in[9];
    const float* wc      = (const float*)d_in[10];
    const float* bc      = (const float*)d_in[11];
    const float* wp      = (const float*)d_in[12];
    const float* bp      = (const float*)d_in[13];
    float* out = (float*)d_out;

    float* ws   = (float*)d_ws;
    float* acc  = ws + ACC_OFF;
    float* deg  = ws + DEG_OFF;
    float* sarr = ws + SARR_OFF;

    k_pre<<<1, 1024, 0, stream>>>(x, w1, b1, gamma, beta, prelu_a, w2, b2, wc, wp,
                                  sarr, N_NODES);

    bool fp16ok = ws_size >= (size_t)NV_BYTE_OFF + (size_t)N_NODES * VD * 2;
    if (fp16ok) {
        k_prep16<<<512, 256, 0, stream>>>(visual, ws, N_NODES);
        k_edge16<<<4096, 256, 0, stream>>>(ei, ws, acc, deg, sarr);
    } else {
        float* inv = ws + INV_OFF;
        k_prep32<<<512, 256, 0, stream>>>(visual, ws, N_NODES);
        k_edge32<<<4096, 256, 0, stream>>>(ei, visual, inv, sarr, acc, deg);
    }
    k_final<<<120, 256, 0, stream>>>(acc, deg, bc, wp, bp, out, N_NODES);
}

// Round 3
// 266.938 us; speedup vs baseline: 2.5975x; 2.5975x over previous
//
#include <hip/hip_runtime.h>
#include <hip/hip_fp16.h>
#include <math.h>

#define N_NODES 30000
#define E_EDGES 480000
#define VD      512
#define HID     32
#define NSTATB  120

// ws layout (float index):
//   [0, 30000)         acc   (zeroed by k_prep16)
//   [30000, 60000)     deg   (zeroed by k_prep16)
//   [60000, 90000)     sarr  (fully written by k_node)
//   [90000, 90600)     stats partials: NSTATB blocks x 5 floats (written by k_statsp)
// byte offset 360448: nvis — normalized fp16 rows, 1024 B each (written by k_prep16)
#define ACC_OFF  0
#define DEG_OFF  30000
#define SARR_OFF 60000
#define STATS_OFF 90000
#define NV_BYTE_OFF 360448u

// ---------------- k_statsp: per-block partial moments of x ----------------
__global__ void __launch_bounds__(256) k_statsp(const float* __restrict__ x,
                                                float* __restrict__ part, int n) {
    __shared__ float red[4][5];
    float s0 = 0.f, s1 = 0.f, s00 = 0.f, s11 = 0.f, s01 = 0.f;
    for (int i = blockIdx.x * blockDim.x + threadIdx.x; i < n; i += gridDim.x * blockDim.x) {
        float2 v = ((const float2*)x)[i];
        s0  += v.x;       s1  += v.y;
        s00 += v.x * v.x; s11 += v.y * v.y;
        s01 += v.x * v.y;
    }
    for (int o = 32; o; o >>= 1) {
        s0  += __shfl_xor(s0,  o, 64);
        s1  += __shfl_xor(s1,  o, 64);
        s00 += __shfl_xor(s00, o, 64);
        s11 += __shfl_xor(s11, o, 64);
        s01 += __shfl_xor(s01, o, 64);
    }
    int wv = threadIdx.x >> 6;
    if ((threadIdx.x & 63) == 0) {
        red[wv][0] = s0; red[wv][1] = s1; red[wv][2] = s00;
        red[wv][3] = s11; red[wv][4] = s01;
    }
    __syncthreads();
    if (threadIdx.x < 5) {
        float v = red[0][threadIdx.x] + red[1][threadIdx.x]
                + red[2][threadIdx.x] + red[3][threadIdx.x];
        part[blockIdx.x * 5 + threadIdx.x] = v;
    }
}

// ---------------- k_node: fold stats, compute per-node scalar s[] ----------------
// s[n] = sb + sum_c prelu(bn(h1))_c * u_c ;  u = (wp.wc).w2  (everything after
// PReLU is linear and projects to a scalar).
__global__ void __launch_bounds__(256) k_node(
        const float* __restrict__ x,
        const float* __restrict__ w1, const float* __restrict__ b1,
        const float* __restrict__ gamma, const float* __restrict__ beta,
        const float* __restrict__ prelu_a,
        const float* __restrict__ w2, const float* __restrict__ b2,
        const float* __restrict__ wc, const float* __restrict__ wp,
        const float* __restrict__ part,
        float* __restrict__ sarr, int n) {
    __shared__ float s_scale[HID], s_shift[HID], s_u[HID], s_w1a[HID], s_w1b[HID];
    __shared__ float s_wpc[HID];
    __shared__ float s_sb;
    int t = threadIdx.x;
    if (t < HID) {
        float S0 = 0, S1 = 0, S00 = 0, S11 = 0, S01 = 0;
        for (int p = 0; p < NSTATB; ++p) {
            S0  += part[p * 5 + 0];
            S1  += part[p * 5 + 1];
            S00 += part[p * 5 + 2];
            S11 += part[p * 5 + 3];
            S01 += part[p * 5 + 4];
        }
        float wpck = 0.f;
        for (int j = 0; j < HID; ++j) wpck += wp[j] * wc[j * HID + t];
        s_wpc[t] = wpck;
        const float invN = 1.0f / (float)n;
        float m0  = S0 * invN, m1 = S1 * invN;
        float v0  = fmaxf(S00 * invN - m0 * m0, 0.f);
        float v1  = fmaxf(S11 * invN - m1 * m1, 0.f);
        float c01 = S01 * invN - m0 * m1;
        float a0 = w1[2 * t], a1 = w1[2 * t + 1];
        float mean = a0 * m0 + a1 * m1 + b1[t];
        float var  = fmaxf(a0 * a0 * v0 + a1 * a1 * v1 + 2.f * a0 * a1 * c01, 0.f);
        float rs    = 1.0f / sqrtf(var + 1e-5f);
        float scale = gamma[t] * rs;
        s_scale[t] = scale;
        s_shift[t] = beta[t] - mean * scale;
        s_w1a[t] = a0; s_w1b[t] = a1;
    }
    __syncthreads();
    if (t < HID) {
        float uu = 0.f;
        for (int k = 0; k < HID; ++k) uu += s_wpc[k] * w2[k * HID + t];
        s_u[t] = uu;
    }
    if (t == 0) {
        float sb = 0.f;
        for (int k = 0; k < HID; ++k) sb += s_wpc[k] * b2[k];
        s_sb = sb;
    }
    __syncthreads();
    const float aslope = prelu_a[0];
    const float sb = s_sb;
    for (int i = blockIdx.x * blockDim.x + t; i < n; i += gridDim.x * blockDim.x) {
        float2 xv = ((const float2*)x)[i];
        float sacc = sb;
        #pragma unroll
        for (int c = 0; c < HID; ++c) {
            float h  = s_w1a[c] * xv.x + s_w1b[c] * xv.y + b1[c];
            float tt = h * s_scale[c] + s_shift[c];
            tt = tt >= 0.f ? tt : aslope * tt;
            sacc += tt * s_u[c];
        }
        sarr[i] = sacc;
    }
}

// ---------------- k_prep16: normalize rows -> fp16, zero acc/deg ----------------
__global__ void __launch_bounds__(256) k_prep16(const float* __restrict__ visual,
                                                float* __restrict__ ws, int n) {
    int gid = blockIdx.x * blockDim.x + threadIdx.x;
    if (gid < 2 * N_NODES) ws[gid] = 0.f;  // acc + deg
    ushort* nvis = (ushort*)((char*)ws + NV_BYTE_OFF);
    int wave  = gid >> 6;
    int lane  = threadIdx.x & 63;
    int nwave = (gridDim.x * blockDim.x) >> 6;
    for (int node = wave; node < n; node += nwave) {
        const float4* row = (const float4*)(visual + (size_t)node * VD);
        float4 a = row[lane];
        float4 b = row[lane + 64];
        float p = a.x*a.x + a.y*a.y + a.z*a.z + a.w*a.w
                + b.x*b.x + b.y*b.y + b.z*b.z + b.w*b.w;
        for (int o = 32; o; o >>= 1) p += __shfl_xor(p, o, 64);
        float r = 1.0f / fmaxf(sqrtf(p), 1e-8f);
        __half2 p0 = __floats2half2_rn(a.x * r, a.y * r);
        __half2 p1 = __floats2half2_rn(a.z * r, a.w * r);
        __half2 p2 = __floats2half2_rn(b.x * r, b.y * r);
        __half2 p3 = __floats2half2_rn(b.z * r, b.w * r);
        uint2* orow = (uint2*)(nvis + (size_t)node * VD);
        uint2 q0, q1;
        q0.x = *(unsigned int*)&p0; q0.y = *(unsigned int*)&p1;
        q1.x = *(unsigned int*)&p2; q1.y = *(unsigned int*)&p3;
        orow[lane]      = q0;
        orow[lane + 64] = q1;
    }
}

// ---------------- k_edge16: cosine (pre-normalized fp16) + scalar scatter ----------------
__device__ inline float2 h2f(unsigned int u) {
    __half2 h = *reinterpret_cast<__half2*>(&u);
    return __half22float2(h);
}

__global__ void __launch_bounds__(256) k_edge16(const int* __restrict__ ei,
                                                const float* __restrict__ ws_ro,
                                                float* __restrict__ acc,
                                                float* __restrict__ deg,
                                                const float* __restrict__ sarr) {
    const uint4* nvis = (const uint4*)((const char*)ws_ro + NV_BYTE_OFF);
    int wave  = (blockIdx.x * blockDim.x + threadIdx.x) >> 6;
    int lane  = threadIdx.x & 63;
    int nwave = (gridDim.x * blockDim.x) >> 6;
    for (int e = wave; e < E_EDGES; e += nwave) {
        int s = ei[e];
        int d = ei[E_EDGES + e];
        uint4 A = nvis[(size_t)s * 64 + lane];
        uint4 B = nvis[(size_t)d * 64 + lane];
        float2 a0 = h2f(A.x), a1 = h2f(A.y), a2 = h2f(A.z), a3 = h2f(A.w);
        float2 b0 = h2f(B.x), b1 = h2f(B.y), b2 = h2f(B.z), b3 = h2f(B.w);
        float p = a0.x*b0.x + a0.y*b0.y + a1.x*b1.x + a1.y*b1.y
                + a2.x*b2.x + a2.y*b2.y + a3.x*b3.x + a3.y*b3.y;
        for (int o = 32; o; o >>= 1) p += __shfl_xor(p, o, 64);
        if (lane == 0) {
            atomicAdd(&acc[d], p * sarr[s]);
            atomicAdd(&deg[d], 1.0f);
        }
    }
}

// ---------------- fp32 fallback path (if ws too small for nvis) ----------------
__global__ void __launch_bounds__(256) k_prep32(const float* __restrict__ visual,
                                                float* __restrict__ ws, int n) {
    int gid = blockIdx.x * blockDim.x + threadIdx.x;
    if (gid < 2 * N_NODES) ws[gid] = 0.f;
    float* inv = ws + STATS_OFF + 5 * NSTATB;
    int wave  = gid >> 6;
    int lane  = threadIdx.x & 63;
    int nwave = (gridDim.x * blockDim.x) >> 6;
    for (int node = wave; node < n; node += nwave) {
        const float4* row = (const float4*)(visual + (size_t)node * VD);
        float4 a = row[lane];
        float4 b = row[lane + 64];
        float p = a.x*a.x + a.y*a.y + a.z*a.z + a.w*a.w
                + b.x*b.x + b.y*b.y + b.z*b.z + b.w*b.w;
        for (int o = 32; o; o >>= 1) p += __shfl_xor(p, o, 64);
        if (lane == 0) inv[node] = 1.0f / fmaxf(sqrtf(p), 1e-8f);
    }
}

__global__ void __launch_bounds__(256) k_edge32(const int* __restrict__ ei,
                                                const float* __restrict__ visual,
                                                const float* __restrict__ inv,
                                                const float* __restrict__ sarr,
                                                float* __restrict__ acc,
                                                float* __restrict__ deg) {
    int wave  = (blockIdx.x * blockDim.x + threadIdx.x) >> 6;
    int lane  = threadIdx.x & 63;
    int nwave = (gridDim.x * blockDim.x) >> 6;
    for (int e = wave; e < E_EDGES; e += nwave) {
        int s = ei[e];
        int d = ei[E_EDGES + e];
        const float4* ra = (const float4*)(visual + (size_t)s * VD);
        const float4* rb = (const float4*)(visual + (size_t)d * VD);
        float4 a0 = ra[lane];
        float4 b0 = rb[lane];
        float4 a1 = ra[lane + 64];
        float4 b1 = rb[lane + 64];
        float p = a0.x*b0.x + a0.y*b0.y + a0.z*b0.z + a0.w*b0.w
                + a1.x*b1.x + a1.y*b1.y + a1.z*b1.z + a1.w*b1.w;
        for (int o = 32; o; o >>= 1) p += __shfl_xor(p, o, 64);
        if (lane == 0) {
            float w = p * inv[s] * inv[d];
            atomicAdd(&acc[d], w * sarr[s]);
            atomicAdd(&deg[d], 1.0f);
        }
    }
}

// ---------------- k_final ----------------
__global__ void k_final(const float* __restrict__ acc, const float* __restrict__ deg,
                        const float* __restrict__ bc, const float* __restrict__ wp,
                        const float* __restrict__ bp, float* __restrict__ out, int n) {
    float K = bp[0];
    #pragma unroll
    for (int j = 0; j < HID; ++j) K += wp[j] * bc[j];
    for (int i = blockIdx.x * blockDim.x + threadIdx.x; i < n; i += gridDim.x * blockDim.x) {
        out[i] = acc[i] / fmaxf(deg[i], 1.0f) + K;
    }
}

extern "C" void kernel_launch(void* const* d_in, const int* in_sizes, int n_in,
                              void* d_out, int out_size, void* d_ws, size_t ws_size,
                              hipStream_t stream) {
    const float* x       = (const float*)d_in[0];
    const float* visual  = (const float*)d_in[1];
    const int*   ei      = (const int*)  d_in[2];
    const float* w1      = (const float*)d_in[3];
    const float* b1      = (const float*)d_in[4];
    const float* gamma   = (const float*)d_in[5];
    const float* beta    = (const float*)d_in[6];
    const float* prelu_a = (const float*)d_in[7];
    const float* w2      = (const float*)d_in[8];
    const float* b2      = (const float*)d_in[9];
    const float* wc      = (const float*)d_in[10];
    const float* bc      = (const float*)d_in[11];
    const float* wp      = (const float*)d_in[12];
    const float* bp      = (const float*)d_in[13];
    float* out = (float*)d_out;

    float* ws   = (float*)d_ws;
    float* acc  = ws + ACC_OFF;
    float* deg  = ws + DEG_OFF;
    float* sarr = ws + SARR_OFF;
    float* part = ws + STATS_OFF;

    k_statsp<<<NSTATB, 256, 0, stream>>>(x, part, N_NODES);
    k_node  <<<256, 256, 0, stream>>>(x, w1, b1, gamma, beta, prelu_a, w2, b2, wc, wp,
                                      part, sarr, N_NODES);

    bool fp16ok = ws_size >= (size_t)NV_BYTE_OFF + (size_t)N_NODES * VD * 2;
    if (fp16ok) {
        k_prep16<<<512, 256, 0, stream>>>(visual, ws, N_NODES);
        k_edge16<<<4096, 256, 0, stream>>>(ei, ws, acc, deg, sarr);
    } else {
        float* inv = ws + STATS_OFF + 5 * NSTATB;
        k_prep32<<<512, 256, 0, stream>>>(visual, ws, N_NODES);
        k_edge32<<<4096, 256, 0, stream>>>(ei, visual, inv, sarr, acc, deg);
    }
    k_final<<<120, 256, 0, stream>>>(acc, deg, bc, wp, bp, out, N_NODES);
}